// Round 10
// baseline (442.440 us; speedup 1.0000x reference)
//
#include <hip/hip_runtime.h>
#include <hip/hip_fp16.h>
#include <math.h>

#define N_NODES   50000
#define N_EDGES   1600000
#define NF        128
#define N_GRAPHS  64
#define N_CLASSES 10

#define NBK       391       // buckets: dst>>7, 128 nodes each (391*128 = 50048)
#define BK_SHIFT  7
#define BK_NODES  128
#define SLAB      5120      // slab capacity/bucket: mean 4096, sigma~64, +16s
#define CHUNK     4096
#define NCHUNKS   ((N_EDGES + CHUNK - 1) / CHUNK)   // 391
#define NODES_PER_BLK 8
#define NBLK_AGG  (N_NODES / NODES_PER_BLK)         // 6250 (exact)
#define N_WAVES   (N_NODES / 2)                     // 25000 pool waves
#define TILE_SHIFT 13                               // src tiles of 8192 nodes
#define NTILE     8                                 // slots (7 used)

typedef _Float16 half8 __attribute__((ext_vector_type(8)));
typedef float f32x4 __attribute__((ext_vector_type(4)));

// ------------------------------------------------- init: cursors+sums+wconv
// blocks 0..2: pre-swizzle W into MFMA B-fragment order fp16:
//   wf[((nt*4+kc)*64 + lane)*8 + j] = W[kc*32 + quad*8 + j][nt*16 + (n&15)]
// blocks 3..34: bucket_cur[b]=b*SLAB (static slab bases), sums=0.
__global__ void k_init(int* __restrict__ bucket_cur, float* __restrict__ sums,
                       const float* __restrict__ w0, const float* __restrict__ w1,
                       const float* __restrict__ w2, _Float16* __restrict__ wf) {
    int b = blockIdx.x, t = threadIdx.x;
    if (b < 3) {
        const float* W = (b == 0) ? w0 : (b == 1) ? w1 : w2;
        _Float16* dst = wf + (size_t)b * NF * NF;
        for (int idx = t; idx < NF * NF; idx += 256) {
            int k = idx >> 7, n = idx & 127;
            int nt = n >> 4, kc = k >> 5, quad = (k >> 3) & 3, j = k & 7;
            int lane = quad * 16 + (n & 15);
            dst[((nt * 4 + kc) * 64 + lane) * 8 + j] = (_Float16)W[idx];
        }
    } else {
        int i = (b - 3) * 256 + t;
        if (i < NBK) bucket_cur[i] = i * SLAB;
        if (i < N_GRAPHS * NF) sums[i] = 0.f;
    }
}

// ------------- P1: scatter packed (src<<7|dstlocal) into bucket slabs
// Per-wg LDS histogram -> one global reservation per (wg,bucket) -> each wg
// owns contiguous runs (round-2's direct scatter wrote 101 MB HBM for
// 6.4 MB payload; reservation keeps L2 lines whole).
__global__ __launch_bounds__(256) void k_bscatter(const int* __restrict__ src,
                                                  const int* __restrict__ dst,
                                                  int* __restrict__ bucket_cur,
                                                  int* __restrict__ pairs) {
    __shared__ int h[NBK], rb[NBK], c2[NBK];
    int t = threadIdx.x;
    for (int i = t; i < NBK; i += 256) { h[i] = 0; c2[i] = 0; }
    __syncthreads();
    int base = blockIdx.x * CHUNK;
    int end = min(base + CHUNK, N_EDGES);
    for (int e = base + t; e < end; e += 256)
        atomicAdd(&h[dst[e] >> BK_SHIFT], 1);
    __syncthreads();
    for (int i = t; i < NBK; i += 256)
        rb[i] = h[i] ? atomicAdd(&bucket_cur[i], h[i]) : 0;
    __syncthreads();
    for (int e = base + t; e < end; e += 256) {
        int d = dst[e];
        int b = d >> BK_SHIFT;
        int k = atomicAdd(&c2[b], 1);
        pairs[rb[b] + k] = (src[e] << BK_SHIFT) | (d & (BK_NODES - 1));
    }
}

// ----------------- P2: per-bucket CSR finalize, src-TILE-sorted rows.
// Rows are ordered by (local dst, src>>13): concurrent agg waves then walk
// H in ~2.1 MB tile phases, raising per-XCD L2 hit rate (round-9 FETCH was
// 152 MB = 12x re-fetch of the 12.8 MB H table).
__global__ __launch_bounds__(512) void k_bfill(const int* __restrict__ pairs,
                                               const int* __restrict__ bucket_cur,
                                               int* __restrict__ row_start,
                                               int* __restrict__ row_end,
                                               float* __restrict__ dis,
                                               int* __restrict__ csr_src) {
    __shared__ int cnt[BK_NODES * NTILE];        // (dstlocal, tile) counters
    __shared__ int cur[BK_NODES * NTILE];
    __shared__ int pos[BK_NODES * NTILE + 1];
    __shared__ int ts[512];
    int b = blockIdx.x, t = threadIdx.x;
    int node_base = b << BK_SHIFT;
    int lo = b * SLAB, hi = bucket_cur[b];

    cnt[t] = 0; cnt[t + 512] = 0;
    __syncthreads();
    for (int e = lo + t; e < hi; e += 512) {
        int p = pairs[e];
        atomicAdd(&cnt[(p & (BK_NODES - 1)) * NTILE + (p >> (BK_SHIFT + TILE_SHIFT))], 1);
    }
    __syncthreads();

    int a0 = cnt[2 * t], a1 = cnt[2 * t + 1];
    ts[t] = a0 + a1;
    __syncthreads();
    for (int off = 1; off < 512; off <<= 1) {
        int y = (t >= off) ? ts[t - off] : 0;
        __syncthreads();
        ts[t] += y;
        __syncthreads();
    }
    int ex = lo + ts[t] - (a0 + a1);             // exclusive within slab
    pos[2 * t] = ex;       cur[2 * t] = ex;
    pos[2 * t + 1] = ex + a0; cur[2 * t + 1] = ex + a0;
    if (t == 511) pos[1024] = lo + ts[511];
    __syncthreads();

    if (t < BK_NODES) {
        int n = node_base + t;
        if (n < N_NODES) {
            int r0 = pos[t * NTILE], r1 = pos[(t + 1) * NTILE];
            row_start[n] = r0;
            row_end[n]   = r1;
            dis[n] = rsqrtf((float)(r1 - r0 + 1));   // deg incl. self-loop
        }
    }
    __syncthreads();

    for (int e = lo + t; e < hi; e += 512) {
        int p = pairs[e];
        int idx = (p & (BK_NODES - 1)) * NTILE + (p >> (BK_SHIFT + TILE_SHIFT));
        int ps = atomicAdd(&cur[idx], 1);
        csr_src[ps] = p >> BK_SHIFT;
    }
}

// ------------------------------------------------------------- MFMA GEMM
// H'[r][c] = dis[r] * sum_k act(X[r][k]) * W[k][c]; fp32 acc, fp16 out.
// FP32IN: layer 0 reads x fp32 directly. mfma_f32_16x16x32_f16:
// A[m=lane&15][k=quad*8+j] from LDS (pad 136); B-frags pre-swizzled
// (coalesced 16B/lane, L2-hot); C/D: D[row=quad*4+reg][col=lane&15]
// (m89/m91). Epilogue: LDS transpose -> coalesced half8 stores.
template <bool ELU, bool FP32IN>
__global__ __launch_bounds__(256) void k_gemm(const void* __restrict__ Xv,
                                              const _Float16* __restrict__ WF,
                                              const float* __restrict__ dis,
                                              __half* __restrict__ H) {
    __shared__ _Float16 xs[64 * 136];
    const _Float16* Xh = (const _Float16*)Xv;
    const float*    Xf = (const float*)Xv;
    int t = threadIdx.x;
    int row0 = blockIdx.x * 64;
#pragma unroll
    for (int i = 0; i < 4; i++) {
        int f = i * 256 + t;              // 0..1023 : 64 rows x 16 half8
        int r = f >> 4, c = (f & 15) * 8;
        int gr = row0 + r;
        half8 v = {};
        if (gr < N_NODES) {
            if (FP32IN) {
                float4 v0 = *(const float4*)&Xf[(size_t)gr * NF + c];
                float4 v1 = *(const float4*)&Xf[(size_t)gr * NF + c + 4];
                v[0] = (_Float16)v0.x; v[1] = (_Float16)v0.y;
                v[2] = (_Float16)v0.z; v[3] = (_Float16)v0.w;
                v[4] = (_Float16)v1.x; v[5] = (_Float16)v1.y;
                v[6] = (_Float16)v1.z; v[7] = (_Float16)v1.w;
            } else {
                v = *(const half8*)&Xh[(size_t)gr * NF + c];
            }
        }
        if (ELU) {
#pragma unroll
            for (int j = 0; j < 8; j++) {
                float xv = (float)v[j];
                v[j] = (_Float16)(xv > 0.f ? xv : (expf(xv) - 1.f));
            }
        }
        *(half8*)&xs[r * 136 + c] = v;
    }
    __syncthreads();

    int w = t >> 6;              // wave id: rows w*16..w*16+15
    int lane = t & 63;
    int m = lane & 15, quad = lane >> 4;

    half8 a[4];
#pragma unroll
    for (int kc = 0; kc < 4; kc++)
        a[kc] = *(const half8*)&xs[(w * 16 + m) * 136 + kc * 32 + quad * 8];

    f32x4 acc[8];
#pragma unroll
    for (int nt = 0; nt < 8; nt++) {
        f32x4 c4 = {0.f, 0.f, 0.f, 0.f};
#pragma unroll
        for (int kc = 0; kc < 4; kc++) {
            half8 bf = *(const half8*)&WF[((nt * 4 + kc) * 64 + lane) * 8];
            c4 = __builtin_amdgcn_mfma_f32_16x16x32_f16(a[kc], bf, c4, 0, 0, 0);
        }
        acc[nt] = c4;
    }

    __syncthreads();                      // all waves done reading xs
#pragma unroll
    for (int reg = 0; reg < 4; reg++) {
        int r = w * 16 + quad * 4 + reg;
        int gr = row0 + r;
        float ds = (gr < N_NODES) ? dis[gr] : 0.f;
#pragma unroll
        for (int nt = 0; nt < 8; nt++)
            xs[r * 136 + nt * 16 + m] = (_Float16)(ds * acc[nt][reg]);
    }
    __syncthreads();
#pragma unroll
    for (int i = 0; i < 4; i++) {
        int f = i * 256 + t;
        int r = f >> 4, c = (f & 15) * 8;
        int gr = row0 + r;
        if (gr < N_NODES)
            *(half8*)&H[(size_t)gr * NF + c] = *(const half8*)&xs[r * 136 + c];
    }
}

// ------------------------------------------------------------- aggregation
// 2 nodes per wave: 32 lanes x 8 B (4 halves) per row.
// out[i] = dis[i]*(sum_src H'[src] + H'[i]) + b ; H' = dis (.) H.
// POOL (layer 2): barrier-free. Round-8/9's block-level reduce needed a
// __syncthreads after the gather -> every wave waited on the block's
// slowest row (54 -> 76 us). Now: shfl-reduce the wave's 2 nodes
// (lanes 0-31 += lanes 32-63) and store one float4/lane to partialw[wave];
// only non-uniform waves (<64) atomic into sums. Contained => uniform, so
// k_head's range-sum sees each node exactly once.
template <bool POOL>
__global__ __launch_bounds__(256) void k_agg(const __half* __restrict__ H,
                                             const float* __restrict__ bias,
                                             const int* __restrict__ row_start,
                                             const int* __restrict__ row_end,
                                             const int* __restrict__ csr_src,
                                             const float* __restrict__ dis,
                                             const int* __restrict__ batch,
                                             float* __restrict__ partialw,
                                             float* __restrict__ sums,
                                             void* __restrict__ outv) {
    const uint2* H4 = (const uint2*)H;      // 8 B = 4 halves; row stride 32
    int t = threadIdx.x;
    int lane = t & 63;
    int node = blockIdx.x * NODES_PER_BLK + (t >> 6) * 2 + (lane >> 5);
    int l    = lane & 31;
    int c    = l * 4;
    float o0 = 0.f, o1 = 0.f, o2 = 0.f, o3 = 0.f;
    bool active = node < N_NODES;
    if (active) {
        int rs = row_start[node], re = row_end[node];
        float a0 = 0.f, a1 = 0.f, a2 = 0.f, a3 = 0.f;
        int e = rs;
        for (; e + 7 < re; e += 8) {
            uint2 v[8];
#pragma unroll
            for (int j = 0; j < 8; j++) {
                int s = csr_src[e + j];
                v[j] = H4[(size_t)s * 32 + l];
            }
#pragma unroll
            for (int j = 0; j < 8; j++) {
                float2 lo = __half22float2(*(__half2*)&v[j].x);
                float2 hi = __half22float2(*(__half2*)&v[j].y);
                a0 += lo.x; a1 += lo.y; a2 += hi.x; a3 += hi.y;
            }
        }
        for (; e < re; e++) {
            int s = csr_src[e];
            uint2 v = H4[(size_t)s * 32 + l];
            float2 lo = __half22float2(*(__half2*)&v.x);
            float2 hi = __half22float2(*(__half2*)&v.y);
            a0 += lo.x; a1 += lo.y; a2 += hi.x; a3 += hi.y;
        }
        {
            uint2 v = H4[(size_t)node * 32 + l];     // self-loop term
            float2 lo = __half22float2(*(__half2*)&v.x);
            float2 hi = __half22float2(*(__half2*)&v.y);
            a0 += lo.x; a1 += lo.y; a2 += hi.x; a3 += hi.y;
        }
        float di = dis[node];
        float4 bv = *(const float4*)&bias[c];
        o0 = a0 * di + bv.x; o1 = a1 * di + bv.y;
        o2 = a2 * di + bv.z; o3 = a3 * di + bv.w;
        if (!POOL) {
            uint2 o;
            *(__half2*)&o.x = __floats2half2_rn(o0, o1);
            *(__half2*)&o.y = __floats2half2_rn(o2, o3);
            ((uint2*)outv)[(size_t)node * 32 + l] = o;
        }
    }
    if (POOL) {
        int node0 = blockIdx.x * NODES_PER_BLK + (t >> 6) * 2;
        int wave_id = node0 >> 1;
        float s0 = o0 + __shfl_down(o0, 32);
        float s1 = o1 + __shfl_down(o1, 32);
        float s2 = o2 + __shfl_down(o2, 32);
        float s3 = o3 + __shfl_down(o3, 32);
        int n1 = min(node0 + 1, N_NODES - 1);
        if (batch[node0] == batch[n1]) {         // uniform wave (99.7%)
            if (lane < 32)
                *(float4*)&partialw[(size_t)wave_id * NF + c] = make_float4(s0, s1, s2, s3);
        } else if (active) {                     // graph-boundary wave
            int g = batch[node];
            atomicAdd(&sums[g * NF + c + 0], o0);
            atomicAdd(&sums[g * NF + c + 1], o1);
            atomicAdd(&sums[g * NF + c + 2], o2);
            atomicAdd(&sums[g * NF + c + 3], o3);
        }
    }
}

// ---------------------------------------------------------------- heads
// Sums each graph's fully-contained pool waves [ceil(s0/2), floor(s1/2))
// (contained <=> uniform), plus boundary contributions in sums.
__global__ void k_head(const float* __restrict__ sums, const float* __restrict__ partialw,
                       const int* __restrict__ batch,
                       const float* __restrict__ wc, const float* __restrict__ bc,
                       const float* __restrict__ wr, const float* __restrict__ br,
                       float* __restrict__ out) {
    __shared__ float p[128];
    __shared__ int sh[2];
    int g = blockIdx.x, c = threadIdx.x;
    if (c < 2) {
        int tgt = g + c;                 // c==0: start of g; c==1: start of g+1
        int lo = 0, hi = N_NODES;
        while (lo < hi) { int m = (lo + hi) >> 1; if (batch[m] < tgt) lo = m + 1; else hi = m; }
        sh[c] = lo;
    }
    __syncthreads();
    int s0 = sh[0], s1 = sh[1];
    float acc = sums[g * NF + c];
    int js = (s0 + 1) >> 1;
    int je = s1 >> 1;
    for (int j = js; j < je; j++) acc += partialw[(size_t)j * NF + c];
    float cnt = (float)max(s1 - s0, 1);
    float pv = acc / cnt;
    p[c] = pv;
    out[g * NF + c] = pv;
    __syncthreads();
    if (c < N_CLASSES) {
        float d = bc[c];
        for (int k = 0; k < NF; k++) d += p[k] * wc[k * N_CLASSES + c];
        out[N_GRAPHS * NF + g * N_CLASSES + c] = d;
    }
    if (c == N_CLASSES) {
        float d = br[0];
        for (int k = 0; k < NF; k++) d += p[k] * wr[k];
        out[N_GRAPHS * NF + N_GRAPHS * N_CLASSES + g] = d;
    }
}

// ================================================================= launch
extern "C" void kernel_launch(void* const* d_in, const int* in_sizes, int n_in,
                              void* d_out, int out_size, void* d_ws, size_t ws_size,
                              hipStream_t stream) {
    const float* x     = (const float*)d_in[0];
    const int*   ei    = (const int*)d_in[1];
    const int*   batch = (const int*)d_in[2];
    const float* w0 = (const float*)d_in[3];
    const float* b0 = (const float*)d_in[4];
    const float* w1 = (const float*)d_in[5];
    const float* b1 = (const float*)d_in[6];
    const float* w2 = (const float*)d_in[7];
    const float* b2 = (const float*)d_in[8];
    const float* wc = (const float*)d_in[9];
    const float* bc = (const float*)d_in[10];
    const float* wr = (const float*)d_in[11];
    const float* br = (const float*)d_in[12];
    const int* srcp = ei;
    const int* dstp = ei + N_EDGES;
    float* out = (float*)d_out;

    char* ws = (char*)d_ws;
    size_t off = 0;
    auto alloc = [&](size_t bytes) -> void* {
        void* p = ws + off;
        off = (off + bytes + 255) & ~(size_t)255;
        return p;
    };
    int*      row_start  = (int*)alloc(N_NODES * 4);
    int*      row_end    = (int*)alloc(N_NODES * 4);
    int*      bucket_cur = (int*)alloc(NBK * 4);
    float*    dis        = (float*)alloc(N_NODES * 4);
    int*      csr_src    = (int*)alloc((size_t)NBK * SLAB * 4);   // slab layout
    __half*   Hbuf       = (__half*)alloc((size_t)N_NODES * NF * 2);
    _Float16* Ah         = (_Float16*)alloc((size_t)N_NODES * NF * 2);
    _Float16* wf         = (_Float16*)alloc((size_t)3 * NF * NF * 2);
    float*    sums       = (float*)alloc(N_GRAPHS * NF * 4);
    float*    partialw   = (float*)alloc((size_t)N_WAVES * NF * 4);  // 12.8 MB
    (void)ws_size;
    // pairs (8 MB slab) aliases Hbuf (12.8 MB): dead after k_bfill; Hbuf is
    // first written by gemm0 (stream-ordered after bfill).
    int* pairs = (int*)Hbuf;

    k_init<<<35, 256, 0, stream>>>(bucket_cur, sums, w0, w1, w2, wf);
    k_bscatter<<<NCHUNKS, 256, 0, stream>>>(srcp, dstp, bucket_cur, pairs);
    k_bfill<<<NBK, 512, 0, stream>>>(pairs, bucket_cur, row_start, row_end, dis, csr_src);

    const int gemm_grid = (N_NODES + 63) / 64;   // 782

    // layer 0 (fp32 x read directly)
    k_gemm<false, true><<<gemm_grid, 256, 0, stream>>>(x, wf, dis, Hbuf);
    k_agg<false><<<NBLK_AGG, 256, 0, stream>>>(Hbuf, b0, row_start, row_end, csr_src, dis, batch, partialw, sums, Ah);
    // layer 1
    k_gemm<true, false><<<gemm_grid, 256, 0, stream>>>(Ah, wf + NF * NF, dis, Hbuf);
    k_agg<false><<<NBLK_AGG, 256, 0, stream>>>(Hbuf, b1, row_start, row_end, csr_src, dis, batch, partialw, sums, Ah);
    // layer 2 (pooling fused: barrier-free per-wave partials)
    k_gemm<true, false><<<gemm_grid, 256, 0, stream>>>(Ah, wf + 2 * NF * NF, dis, Hbuf);
    k_agg<true><<<NBLK_AGG, 256, 0, stream>>>(Hbuf, b2, row_start, row_end, csr_src, dis, batch, partialw, sums, nullptr);

    k_head<<<N_GRAPHS, 128, 0, stream>>>(sums, partialw, batch, wc, bc, wr, br, out);
}

// Round 11
// 390.121 us; speedup vs baseline: 1.1341x; 1.1341x over previous
//
#include <hip/hip_runtime.h>
#include <hip/hip_fp16.h>
#include <math.h>

#define N_NODES   50000
#define N_EDGES   1600000
#define NF        128
#define N_GRAPHS  64
#define N_CLASSES 10

#define NBK       391       // buckets: dst>>7, 128 nodes each (391*128 = 50048)
#define BK_SHIFT  7
#define BK_NODES  128
#define SLAB      5120      // slab capacity/bucket: mean 4096, sigma~64, +16s
#define CHUNK     4096
#define NCHUNKS   ((N_EDGES + CHUNK - 1) / CHUNK)   // 391
#define NODES_PER_BLK 8
#define NBLK_AGG  (N_NODES / NODES_PER_BLK)         // 6250 (exact)
#define TILE_SHIFT 13                               // src tiles of 8192 nodes
#define NTILE     8                                 // slots (7 used)

typedef _Float16 half8 __attribute__((ext_vector_type(8)));
typedef float f32x4 __attribute__((ext_vector_type(4)));

// ------------------------------------------------- init: cursors+sums+wconv
// blocks 0..2: pre-swizzle W into MFMA B-fragment order fp16:
//   wf[((nt*4+kc)*64 + lane)*8 + j] = W[kc*32 + quad*8 + j][nt*16 + (n&15)]
// blocks 3..34: bucket_cur[b]=b*SLAB (static slab bases), sums=0.
__global__ void k_init(int* __restrict__ bucket_cur, float* __restrict__ sums,
                       const float* __restrict__ w0, const float* __restrict__ w1,
                       const float* __restrict__ w2, _Float16* __restrict__ wf) {
    int b = blockIdx.x, t = threadIdx.x;
    if (b < 3) {
        const float* W = (b == 0) ? w0 : (b == 1) ? w1 : w2;
        _Float16* dst = wf + (size_t)b * NF * NF;
        for (int idx = t; idx < NF * NF; idx += 256) {
            int k = idx >> 7, n = idx & 127;
            int nt = n >> 4, kc = k >> 5, quad = (k >> 3) & 3, j = k & 7;
            int lane = quad * 16 + (n & 15);
            dst[((nt * 4 + kc) * 64 + lane) * 8 + j] = (_Float16)W[idx];
        }
    } else {
        int i = (b - 3) * 256 + t;
        if (i < NBK) bucket_cur[i] = i * SLAB;
        if (i < N_GRAPHS * NF) sums[i] = 0.f;
    }
}

// ------------- P1: scatter packed (src<<7|dstlocal) into bucket slabs
// Per-wg LDS histogram -> one global reservation per (wg,bucket) -> each wg
// owns contiguous runs (round-2's direct scatter wrote 101 MB HBM for
// 6.4 MB payload; reservation keeps L2 lines whole).
__global__ __launch_bounds__(256) void k_bscatter(const int* __restrict__ src,
                                                  const int* __restrict__ dst,
                                                  int* __restrict__ bucket_cur,
                                                  int* __restrict__ pairs) {
    __shared__ int h[NBK], rb[NBK], c2[NBK];
    int t = threadIdx.x;
    for (int i = t; i < NBK; i += 256) { h[i] = 0; c2[i] = 0; }
    __syncthreads();
    int base = blockIdx.x * CHUNK;
    int end = min(base + CHUNK, N_EDGES);
    for (int e = base + t; e < end; e += 256)
        atomicAdd(&h[dst[e] >> BK_SHIFT], 1);
    __syncthreads();
    for (int i = t; i < NBK; i += 256)
        rb[i] = h[i] ? atomicAdd(&bucket_cur[i], h[i]) : 0;
    __syncthreads();
    for (int e = base + t; e < end; e += 256) {
        int d = dst[e];
        int b = d >> BK_SHIFT;
        int k = atomicAdd(&c2[b], 1);
        pairs[rb[b] + k] = (src[e] << BK_SHIFT) | (d & (BK_NODES - 1));
    }
}

// ----------------- P2: per-bucket CSR finalize, src-TILE-sorted rows.
// Rows are ordered by (local dst, src>>13): concurrent agg waves walk H in
// ~2.1 MB tile phases, raising per-XCD L2 hit rate on the gather.
__global__ __launch_bounds__(512) void k_bfill(const int* __restrict__ pairs,
                                               const int* __restrict__ bucket_cur,
                                               int* __restrict__ row_start,
                                               int* __restrict__ row_end,
                                               float* __restrict__ dis,
                                               int* __restrict__ csr_src) {
    __shared__ int cnt[BK_NODES * NTILE];        // (dstlocal, tile) counters
    __shared__ int cur[BK_NODES * NTILE];
    __shared__ int pos[BK_NODES * NTILE + 1];
    __shared__ int ts[512];
    int b = blockIdx.x, t = threadIdx.x;
    int node_base = b << BK_SHIFT;
    int lo = b * SLAB, hi = bucket_cur[b];

    cnt[t] = 0; cnt[t + 512] = 0;
    __syncthreads();
    for (int e = lo + t; e < hi; e += 512) {
        int p = pairs[e];
        atomicAdd(&cnt[(p & (BK_NODES - 1)) * NTILE + (p >> (BK_SHIFT + TILE_SHIFT))], 1);
    }
    __syncthreads();

    int a0 = cnt[2 * t], a1 = cnt[2 * t + 1];
    ts[t] = a0 + a1;
    __syncthreads();
    for (int off = 1; off < 512; off <<= 1) {
        int y = (t >= off) ? ts[t - off] : 0;
        __syncthreads();
        ts[t] += y;
        __syncthreads();
    }
    int ex = lo + ts[t] - (a0 + a1);             // exclusive within slab
    pos[2 * t] = ex;       cur[2 * t] = ex;
    pos[2 * t + 1] = ex + a0; cur[2 * t + 1] = ex + a0;
    if (t == 511) pos[1024] = lo + ts[511];
    __syncthreads();

    if (t < BK_NODES) {
        int n = node_base + t;
        if (n < N_NODES) {
            int r0 = pos[t * NTILE], r1 = pos[(t + 1) * NTILE];
            row_start[n] = r0;
            row_end[n]   = r1;
            dis[n] = rsqrtf((float)(r1 - r0 + 1));   // deg incl. self-loop
        }
    }
    __syncthreads();

    for (int e = lo + t; e < hi; e += 512) {
        int p = pairs[e];
        int idx = (p & (BK_NODES - 1)) * NTILE + (p >> (BK_SHIFT + TILE_SHIFT));
        int ps = atomicAdd(&cur[idx], 1);
        csr_src[ps] = p >> BK_SHIFT;
    }
}

// ------------------------------------------------------------- MFMA GEMM
// H'[r][c] = dis[r] * sum_k act(X[r][k]) * W[k][c]; fp32 acc, fp16 out.
// FP32IN: layer 0 reads x fp32 directly. mfma_f32_16x16x32_f16:
// A[m=lane&15][k=quad*8+j] from LDS (pad 136); B-frags pre-swizzled
// (coalesced 16B/lane, L2-hot); C/D: D[row=quad*4+reg][col=lane&15]
// (m89/m91). Epilogue: LDS transpose -> coalesced half8 stores.
template <bool ELU, bool FP32IN>
__global__ __launch_bounds__(256) void k_gemm(const void* __restrict__ Xv,
                                              const _Float16* __restrict__ WF,
                                              const float* __restrict__ dis,
                                              __half* __restrict__ H) {
    __shared__ _Float16 xs[64 * 136];
    const _Float16* Xh = (const _Float16*)Xv;
    const float*    Xf = (const float*)Xv;
    int t = threadIdx.x;
    int row0 = blockIdx.x * 64;
#pragma unroll
    for (int i = 0; i < 4; i++) {
        int f = i * 256 + t;              // 0..1023 : 64 rows x 16 half8
        int r = f >> 4, c = (f & 15) * 8;
        int gr = row0 + r;
        half8 v = {};
        if (gr < N_NODES) {
            if (FP32IN) {
                float4 v0 = *(const float4*)&Xf[(size_t)gr * NF + c];
                float4 v1 = *(const float4*)&Xf[(size_t)gr * NF + c + 4];
                v[0] = (_Float16)v0.x; v[1] = (_Float16)v0.y;
                v[2] = (_Float16)v0.z; v[3] = (_Float16)v0.w;
                v[4] = (_Float16)v1.x; v[5] = (_Float16)v1.y;
                v[6] = (_Float16)v1.z; v[7] = (_Float16)v1.w;
            } else {
                v = *(const half8*)&Xh[(size_t)gr * NF + c];
            }
        }
        if (ELU) {
#pragma unroll
            for (int j = 0; j < 8; j++) {
                float xv = (float)v[j];
                v[j] = (_Float16)(xv > 0.f ? xv : (expf(xv) - 1.f));
            }
        }
        *(half8*)&xs[r * 136 + c] = v;
    }
    __syncthreads();

    int w = t >> 6;              // wave id: rows w*16..w*16+15
    int lane = t & 63;
    int m = lane & 15, quad = lane >> 4;

    half8 a[4];
#pragma unroll
    for (int kc = 0; kc < 4; kc++)
        a[kc] = *(const half8*)&xs[(w * 16 + m) * 136 + kc * 32 + quad * 8];

    f32x4 acc[8];
#pragma unroll
    for (int nt = 0; nt < 8; nt++) {
        f32x4 c4 = {0.f, 0.f, 0.f, 0.f};
#pragma unroll
        for (int kc = 0; kc < 4; kc++) {
            half8 bf = *(const half8*)&WF[((nt * 4 + kc) * 64 + lane) * 8];
            c4 = __builtin_amdgcn_mfma_f32_16x16x32_f16(a[kc], bf, c4, 0, 0, 0);
        }
        acc[nt] = c4;
    }

    __syncthreads();                      // all waves done reading xs
#pragma unroll
    for (int reg = 0; reg < 4; reg++) {
        int r = w * 16 + quad * 4 + reg;
        int gr = row0 + r;
        float ds = (gr < N_NODES) ? dis[gr] : 0.f;
#pragma unroll
        for (int nt = 0; nt < 8; nt++)
            xs[r * 136 + nt * 16 + m] = (_Float16)(ds * acc[nt][reg]);
    }
    __syncthreads();
#pragma unroll
    for (int i = 0; i < 4; i++) {
        int f = i * 256 + t;
        int r = f >> 4, c = (f & 15) * 8;
        int gr = row0 + r;
        if (gr < N_NODES)
            *(half8*)&H[(size_t)gr * NF + c] = *(const half8*)&xs[r * 136 + c];
    }
}

// ------------------------------------------------------------- aggregation
// 2 nodes per wave: 32 lanes x 8 B (4 halves) per row.
// out[i] = dis[i]*(sum_src H'[src] + H'[i]) + b ; H' = dis (.) H.
// All layers emit fp16 per-node output (layer 2 feeds k_pool). Fused-pool
// variants (rounds 8/9/10: hot atomics / block barrier / serial reduce)
// all lost to this plain form + separate pool.
__global__ __launch_bounds__(256) void k_agg(const __half* __restrict__ H,
                                             const float* __restrict__ bias,
                                             const int* __restrict__ row_start,
                                             const int* __restrict__ row_end,
                                             const int* __restrict__ csr_src,
                                             const float* __restrict__ dis,
                                             __half* __restrict__ outh) {
    const uint2* H4 = (const uint2*)H;      // 8 B = 4 halves; row stride 32
    int t = threadIdx.x;
    int lane = t & 63;
    int node = blockIdx.x * NODES_PER_BLK + (t >> 6) * 2 + (lane >> 5);
    int l    = lane & 31;
    if (node >= N_NODES) return;
    int rs = row_start[node], re = row_end[node];
    float a0 = 0.f, a1 = 0.f, a2 = 0.f, a3 = 0.f;
    int e = rs;
    for (; e + 7 < re; e += 8) {
        uint2 v[8];
#pragma unroll
        for (int j = 0; j < 8; j++) {
            int s = csr_src[e + j];
            v[j] = H4[(size_t)s * 32 + l];
        }
#pragma unroll
        for (int j = 0; j < 8; j++) {
            float2 lo = __half22float2(*(__half2*)&v[j].x);
            float2 hi = __half22float2(*(__half2*)&v[j].y);
            a0 += lo.x; a1 += lo.y; a2 += hi.x; a3 += hi.y;
        }
    }
    for (; e < re; e++) {
        int s = csr_src[e];
        uint2 v = H4[(size_t)s * 32 + l];
        float2 lo = __half22float2(*(__half2*)&v.x);
        float2 hi = __half22float2(*(__half2*)&v.y);
        a0 += lo.x; a1 += lo.y; a2 += hi.x; a3 += hi.y;
    }
    {
        uint2 v = H4[(size_t)node * 32 + l];     // self-loop term
        float2 lo = __half22float2(*(__half2*)&v.x);
        float2 hi = __half22float2(*(__half2*)&v.y);
        a0 += lo.x; a1 += lo.y; a2 += hi.x; a3 += hi.y;
    }
    float di = dis[node];
    int c = l * 4;
    float4 bv = *(const float4*)&bias[c];
    uint2 o;
    *(__half2*)&o.x = __floats2half2_rn(a0 * di + bv.x, a1 * di + bv.y);
    *(__half2*)&o.y = __floats2half2_rn(a2 * di + bv.z, a3 * di + bv.w);
    ((uint2*)outh)[(size_t)node * 32 + l] = o;
}

// ---------------------------------------------------------------- pooling
// batch sorted; block = 256 contiguous nodes, threads = 2 half-groups x 128
// features; run-length accumulate in fp32, one atomic per (graph-run, feat).
// Proven structure (rounds 2-7); now reads fp16 A.
__global__ void k_pool(const __half* __restrict__ A, const int* __restrict__ batch,
                       float* __restrict__ sums) {
    int b = blockIdx.x, t = threadIdx.x;
    int c = t & 127, th = t >> 7;
    int start = b * 256 + th;
    if (start >= N_NODES) return;
    int end = min(N_NODES, b * 256 + 256);
    float acc = 0.f;
    int gcur = batch[start];
    for (int i = start; i < end; i += 2) {
        int g = batch[i];
        if (g != gcur) {
            atomicAdd(&sums[gcur * NF + c], acc);
            acc = 0.f;
            gcur = g;
        }
        acc += __half2float(A[(size_t)i * NF + c]);
    }
    atomicAdd(&sums[gcur * NF + c], acc);
}

// ---------------------------------------------------------------- heads
__global__ void k_head(const float* __restrict__ sums, const int* __restrict__ batch,
                       const float* __restrict__ wc, const float* __restrict__ bc,
                       const float* __restrict__ wr, const float* __restrict__ br,
                       float* __restrict__ out) {
    __shared__ float p[128];
    __shared__ int sh[2];
    int g = blockIdx.x, c = threadIdx.x;
    if (c < 2) {
        int tgt = g + c;                 // c==0: start of g; c==1: start of g+1
        int lo = 0, hi = N_NODES;
        while (lo < hi) { int m = (lo + hi) >> 1; if (batch[m] < tgt) lo = m + 1; else hi = m; }
        sh[c] = lo;
    }
    __syncthreads();
    int s0 = sh[0], s1 = sh[1];
    float cnt = (float)max(s1 - s0, 1);
    float pv = sums[g * NF + c] / cnt;
    p[c] = pv;
    out[g * NF + c] = pv;
    __syncthreads();
    if (c < N_CLASSES) {
        float d = bc[c];
        for (int k = 0; k < NF; k++) d += p[k] * wc[k * N_CLASSES + c];
        out[N_GRAPHS * NF + g * N_CLASSES + c] = d;
    }
    if (c == N_CLASSES) {
        float d = br[0];
        for (int k = 0; k < NF; k++) d += p[k] * wr[k];
        out[N_GRAPHS * NF + N_GRAPHS * N_CLASSES + g] = d;
    }
}

// ================================================================= launch
extern "C" void kernel_launch(void* const* d_in, const int* in_sizes, int n_in,
                              void* d_out, int out_size, void* d_ws, size_t ws_size,
                              hipStream_t stream) {
    const float* x     = (const float*)d_in[0];
    const int*   ei    = (const int*)d_in[1];
    const int*   batch = (const int*)d_in[2];
    const float* w0 = (const float*)d_in[3];
    const float* b0 = (const float*)d_in[4];
    const float* w1 = (const float*)d_in[5];
    const float* b1 = (const float*)d_in[6];
    const float* w2 = (const float*)d_in[7];
    const float* b2 = (const float*)d_in[8];
    const float* wc = (const float*)d_in[9];
    const float* bc = (const float*)d_in[10];
    const float* wr = (const float*)d_in[11];
    const float* br = (const float*)d_in[12];
    const int* srcp = ei;
    const int* dstp = ei + N_EDGES;
    float* out = (float*)d_out;

    char* ws = (char*)d_ws;
    size_t off = 0;
    auto alloc = [&](size_t bytes) -> void* {
        void* p = ws + off;
        off = (off + bytes + 255) & ~(size_t)255;
        return p;
    };
    int*      row_start  = (int*)alloc(N_NODES * 4);
    int*      row_end    = (int*)alloc(N_NODES * 4);
    int*      bucket_cur = (int*)alloc(NBK * 4);
    float*    dis        = (float*)alloc(N_NODES * 4);
    int*      csr_src    = (int*)alloc((size_t)NBK * SLAB * 4);   // slab layout
    __half*   Hbuf       = (__half*)alloc((size_t)N_NODES * NF * 2);
    _Float16* Ah         = (_Float16*)alloc((size_t)N_NODES * NF * 2);
    _Float16* wf         = (_Float16*)alloc((size_t)3 * NF * NF * 2);
    float*    sums       = (float*)alloc(N_GRAPHS * NF * 4);
    (void)ws_size;
    // pairs (8 MB slab) aliases Hbuf (12.8 MB): dead after k_bfill; Hbuf is
    // first written by gemm0 (stream-ordered after bfill).
    int* pairs = (int*)Hbuf;

    k_init<<<35, 256, 0, stream>>>(bucket_cur, sums, w0, w1, w2, wf);
    k_bscatter<<<NCHUNKS, 256, 0, stream>>>(srcp, dstp, bucket_cur, pairs);
    k_bfill<<<NBK, 512, 0, stream>>>(pairs, bucket_cur, row_start, row_end, dis, csr_src);

    const int gemm_grid = (N_NODES + 63) / 64;   // 782

    // layer 0 (fp32 x read directly)
    k_gemm<false, true><<<gemm_grid, 256, 0, stream>>>(x, wf, dis, Hbuf);
    k_agg<<<NBLK_AGG, 256, 0, stream>>>(Hbuf, b0, row_start, row_end, csr_src, dis, (__half*)Ah);
    // layer 1
    k_gemm<true, false><<<gemm_grid, 256, 0, stream>>>(Ah, wf + NF * NF, dis, Hbuf);
    k_agg<<<NBLK_AGG, 256, 0, stream>>>(Hbuf, b1, row_start, row_end, csr_src, dis, (__half*)Ah);
    // layer 2 (fp16 out, pooled by k_pool)
    k_gemm<true, false><<<gemm_grid, 256, 0, stream>>>(Ah, wf + 2 * NF * NF, dis, Hbuf);
    k_agg<<<NBLK_AGG, 256, 0, stream>>>(Hbuf, b2, row_start, row_end, csr_src, dis, (__half*)Ah);

    k_pool<<<(N_NODES + 255) / 256, 256, 0, stream>>>((__half*)Ah, batch, sums);
    k_head<<<N_GRAPHS, 128, 0, stream>>>(sums, batch, wc, bc, wr, br, out);
}